// Round 7
// baseline (439.327 us; speedup 1.0000x reference)
//
#include <hip/hip_runtime.h>

typedef unsigned int uint32;
typedef uint32 v4u __attribute__((ext_vector_type(4)));

#define Bb 32
#define Pp 196
#define Dd 512
#define Hh 8
#define Uu 4
#define Cc 500

// Outputs (float32), concatenated flat:
// out0: known_prompts   (B*C, 11, D) -> 90,112,000 elems
// out1: unknown_prompts (B, 7, D)    -> 114,688 elems @ 90,112,000
// out2: semantic_tokens (B, H, D)    -> 131,072 elems @ 90,226,688
#define OUT1_ELEM_OFF 90112000
#define OUT2_ELEM_OFF 90226688

#define NPC 16   // p-chunks for pooling partials

// ws layout (float element offsets; all 16B-aligned)
#define WS_SC   0          // scores (B,H,P)            = 50,176 floats
#define WS_PART 51200      // pool partials (B,NPC,H,D) = 2,097,152 floats
#define WS_DOM  2148352    // projected_domain (B,D)    = 16,384 floats
#define WS_SEM  2164736    // projected_sem (B,H,D)     = 131,072 floats
#define WS_PP   2295808    // proj k-partials (2,B,H,D) = 262,144 floats

__device__ __forceinline__ float dot4(float4 a, float4 b, float acc) {
    acc = fmaf(a.x, b.x, acc);
    acc = fmaf(a.y, b.y, acc);
    acc = fmaf(a.z, b.z, acc);
    acc = fmaf(a.w, b.w, acc);
    return acc;
}

// ---------------- K1: scores[b,h,p] = patch[b,p,:].query[h,:] ----------------
// grid = B*49 = 1568, block = 256 (4 waves, one p per wave)
__global__ __launch_bounds__(256)
void k_scores(const float* __restrict__ patch, const float* __restrict__ query,
              float* __restrict__ sc) {
    __shared__ float s_q[Hh * Dd];   // 16 KB
    const int b = blockIdx.x / 49;
    const int p0 = (blockIdx.x % 49) * 4;
    const int tid = threadIdx.x;
    for (int j = tid; j < Hh * Dd / 4; j += 256)
        ((float4*)s_q)[j] = ((const float4*)query)[j];
    __syncthreads();

    const int wave = tid >> 6, lane = tid & 63;
    const int p = p0 + wave;
    const float* pr = patch + ((size_t)b * Pp + p) * Dd + lane * 8;
    const float4 v0 = *(const float4*)pr;
    const float4 v1 = *(const float4*)(pr + 4);

    float out = 0.f;
#pragma unroll
    for (int h = 0; h < 8; ++h) {
        const float4 q0 = *(const float4*)&s_q[h * Dd + lane * 8];
        const float4 q1 = *(const float4*)&s_q[h * Dd + lane * 8 + 4];
        float a = dot4(v0, q0, 0.f);
        a = dot4(v1, q1, a);
#pragma unroll
        for (int m = 32; m >= 1; m >>= 1) a += __shfl_xor(a, m, 64);
        if (lane == h) out = a;
    }
    if (lane < 8) sc[((size_t)b * Hh + lane) * Pp + p] = out;
}

// ---------------- K2: softmax (in-block) + pooling partials ----------------
// grid = B*NPC = 512 (b, p-chunk of 13), block = 128; thread: 1 float4 of D x all 8 h
__global__ __launch_bounds__(128)
void k_pool_part(const float* __restrict__ patch, const float* __restrict__ sc,
                 float* __restrict__ part) {
    __shared__ float s_w[Hh * Pp];   // scores -> weights, 6.3 KB
    const int b = blockIdx.x >> 4;
    const int pc = blockIdx.x & 15;
    const int tid = threadIdx.x;

    for (int j = tid; j < Hh * Pp; j += 128) s_w[j] = sc[(size_t)b * Hh * Pp + j];
    __syncthreads();

    // softmax over p: h = tid>>4, 16-lane group (within-wave shuffles)
    {
        const int h = tid >> 4, gl = tid & 15;
        float m = -1e30f;
        for (int p = gl; p < Pp; p += 16) m = fmaxf(m, s_w[h * Pp + p]);
#pragma unroll
        for (int mm = 8; mm >= 1; mm >>= 1) m = fmaxf(m, __shfl_xor(m, mm, 64));
        float s = 0.f;
        for (int p = gl; p < Pp; p += 16) s += __expf(s_w[h * Pp + p] - m);
#pragma unroll
        for (int mm = 8; mm >= 1; mm >>= 1) s += __shfl_xor(s, mm, 64);
        const float inv = 1.f / s;
        for (int p = gl; p < Pp; p += 16)
            s_w[h * Pp + p] = __expf(s_w[h * Pp + p] - m) * inv;  // disjoint p
    }
    __syncthreads();

    const int f = tid;                // float4 index of D (128 covers 512)
    const int pstart = pc * 13;
    const int pend = (pstart + 13 < Pp) ? pstart + 13 : Pp;
    float4 acc[8];
#pragma unroll
    for (int h = 0; h < 8; ++h) acc[h] = (float4){0, 0, 0, 0};
    const float4* pb4 = (const float4*)(patch + (size_t)b * Pp * Dd);
    for (int p = pstart; p < pend; ++p) {
        const float4 pv = pb4[p * 128 + f];
#pragma unroll
        for (int h = 0; h < 8; ++h) {
            const float w = s_w[h * Pp + p];
            acc[h].x = fmaf(w, pv.x, acc[h].x);
            acc[h].y = fmaf(w, pv.y, acc[h].y);
            acc[h].z = fmaf(w, pv.z, acc[h].z);
            acc[h].w = fmaf(w, pv.w, acc[h].w);
        }
    }
    float4* po = (float4*)part + ((size_t)b * NPC + pc) * 1024;
#pragma unroll
    for (int h = 0; h < 8; ++h) po[h * 128 + f] = acc[h];
}

// ---------------- K3: combine partials -> semantic_tokens (out2) ----------------
// grid = 128, block = 256; one float4 per thread over B*H*D/4 = 32768
__global__ __launch_bounds__(256)
void k_combine(const float* __restrict__ part, float* __restrict__ st) {
    const int idx = blockIdx.x * 256 + threadIdx.x;
    const int b = idx >> 10;
    const int r = idx & 1023;
    const float4* p4 = (const float4*)part;
    float4 a = {0, 0, 0, 0};
#pragma unroll
    for (int pc = 0; pc < NPC; ++pc) {
        const float4 v = p4[((size_t)b * NPC + pc) * 1024 + r];
        a.x += v.x; a.y += v.y; a.z += v.z; a.w += v.w;
    }
    ((float4*)st)[idx] = a;
}

// ---------------- K4: projections, k-split partials ----------------
// grid = 384, block = 128.
// blk<256: sem partial: h = blk>>5, et = (blk&31)>>1, k = blk&1.
//   Stage semW[h, e0:e0+32, d0:d0+256] + st[:, h, d0:d0+256] in LDS float4[32][65]
//   (16B-aligned rows; st-reads 2-way-free, w-reads 4-way ~1.58x per m136).
//   Thread tile 2b x 4e. Partial -> pp, layout (k, b, h, e).
// blk>=256: dom (128 blocks): projected_domain[b,e].
__global__ __launch_bounds__(128)
void k_proj(const float* __restrict__ gf, const float* __restrict__ domW,
            const float* __restrict__ domb, const float* __restrict__ semW,
            const float* __restrict__ st,
            float* __restrict__ dom_ws, float* __restrict__ pp) {
    __shared__ float4 s_w4[32][65];    // 33,280 B
    __shared__ float4 s_st4[32][65];   // 33,280 B
    const int blk = blockIdx.x;
    const int tid = threadIdx.x;
    if (blk < 256) {
        const int h = blk >> 5;
        const int et = (blk & 31) >> 1;
        const int k = blk & 1;
        const int e0 = et * 32;
        // stage: 32 rows x 64 float4 each (coalesced along d)
        for (int g = tid; g < 32 * 64; g += 128) {
            const int r = g >> 6, c4 = g & 63;
            s_w4[r][c4] = ((const float4*)semW)[(size_t)(h * Dd + e0 + r) * 128 + k * 64 + c4];
            s_st4[r][c4] = ((const float4*)st)[(size_t)(r * Hh + h) * 128 + k * 64 + c4];
        }
        __syncthreads();
        const int pe = tid & 7;        // e = e0 + pe*4 + j
        const int pb = tid >> 3;       // b = 2*pb + i
        const float4* w0 = s_w4[pe * 4 + 0];
        const float4* w1 = s_w4[pe * 4 + 1];
        const float4* w2 = s_w4[pe * 4 + 2];
        const float4* w3 = s_w4[pe * 4 + 3];
        const float4* sA = s_st4[2 * pb];
        const float4* sB = s_st4[2 * pb + 1];
        float4 accA = {0, 0, 0, 0}, accB = {0, 0, 0, 0};
#pragma unroll 4
        for (int d4 = 0; d4 < 64; ++d4) {
            const float4 a = sA[d4];
            const float4 b = sB[d4];
            const float4 v0 = w0[d4];
            const float4 v1 = w1[d4];
            const float4 v2 = w2[d4];
            const float4 v3 = w3[d4];
            accA.x = dot4(a, v0, accA.x); accA.y = dot4(a, v1, accA.y);
            accA.z = dot4(a, v2, accA.z); accA.w = dot4(a, v3, accA.w);
            accB.x = dot4(b, v0, accB.x); accB.y = dot4(b, v1, accB.y);
            accB.z = dot4(b, v2, accB.z); accB.w = dot4(b, v3, accB.w);
        }
        // pp layout: ((k*Bb + b)*Hh + h)*Dd + e   -> float4 slab of 32768 per k
        float4* o = (float4*)pp + (size_t)k * 32768;
        o[((2 * pb) * Hh + h) * 128 + et * 8 + pe] = accA;
        o[((2 * pb + 1) * Hh + h) * 128 + et * 8 + pe] = accB;
    } else {
        const int tg = (blk - 256) * 128 + tid;   // 0..16383
        const int b = tg >> 9;
        const int e = tg & 511;
        const float4* wr = (const float4*)(domW + (size_t)e * Dd);
        const float4* gr = (const float4*)(gf + (size_t)b * Dd);
        float acc = domb[e];
#pragma unroll 8
        for (int j = 0; j < Dd / 4; ++j) acc = dot4(gr[j], wr[j], acc);
        dom_ws[b * Dd + e] = acc;
    }
}

// ---------------- K4b: sum k-partials + bias -> projected_sem (b,h,e) ----------------
// grid = 128, block = 256; float4 per thread over B*H*D/4 = 32768.
// idx4 = b*1024 + h*128 + e4; idx4 & 1023 = h*128 + e4 (semb float4 index).
__global__ __launch_bounds__(256)
void k_proj_sum(const float* __restrict__ pp, const float* __restrict__ semb,
                float* __restrict__ sem_ws) {
    const int idx4 = blockIdx.x * 256 + threadIdx.x;
    const float4 a = ((const float4*)pp)[idx4];
    const float4 b = ((const float4*)pp)[32768 + idx4];
    const float4 bias = ((const float4*)semb)[idx4 & 1023];
    float4 o;
    o.x = a.x + b.x + bias.x;
    o.y = a.y + b.y + bias.y;
    o.z = a.z + b.z + bias.z;
    o.w = a.w + b.w + bias.w;
    ((float4*)sem_ws)[idx4] = o;
}

// ---------------- K5: prompt assembly (360 MB streaming write) ----------------
// block = 128; known row = 11 tokens x 128 v4u -> 11 exact unrolled iterations.
// XCD swizzle: c == (blk&7) mod 8 so each XCD's L2 read set is ~1.1 MB.
// grid = 8*63*32 known (+guard c<500) + 32 unknown = 16160.
__global__ __launch_bounds__(128)
void k_assemble(const v4u* __restrict__ pre, const v4u* __restrict__ suf,
                const v4u* __restrict__ dom, const v4u* __restrict__ sem,
                const v4u* __restrict__ upre, const v4u* __restrict__ usuf,
                const v4u* __restrict__ ust,
                v4u* __restrict__ out0, v4u* __restrict__ out1) {
    const int blk = blockIdx.x;
    const int tid = threadIdx.x;
    if (blk < 16128) {
        const int x = blk & 7;
        const int m = blk >> 3;           // 0..2015
        const int b = m / 63;
        const int c = x + 8 * (m % 63);
        if (c >= Cc) return;
        v4u* row = out0 + (size_t)(b * Cc + c) * 1408;
#pragma unroll
        for (int t = 0; t < 11; ++t) {
            v4u v;
            if (t == 0) v = pre[c * 128 + tid];
            else if (t == 10) v = suf[c * 128 + tid];
            else if (t == 1) v = dom[b * 128 + tid];
            else v = sem[b * 1024 + (t - 2) * 128 + tid];
            row[t * 128 + tid] = v;
        }
    } else {
        const int b = blk - 16128;
#pragma unroll
        for (int t = 0; t < 7; ++t) {
            v4u v;
            if (t == 0) v = upre[tid];
            else if (t == 6) v = usuf[tid];
            else if (t == 1) v = dom[b * 128 + tid];
            else v = ust[(t - 2) * 128 + tid];
            out1[b * 896 + t * 128 + tid] = v;
        }
    }
}

extern "C" void kernel_launch(void* const* d_in, const int* in_sizes, int n_in,
                              void* d_out, int out_size, void* d_ws, size_t ws_size,
                              hipStream_t stream) {
    const float* patch = (const float*)d_in[0];   // (B,P,D)
    const float* gf    = (const float*)d_in[1];   // (B,D)
    const float* query = (const float*)d_in[2];   // (H,D)
    const float* domW  = (const float*)d_in[3];   // (D,D)
    const float* domb  = (const float*)d_in[4];   // (D,)
    const float* semW  = (const float*)d_in[5];   // (H,D,D)
    const float* semb  = (const float*)d_in[6];   // (H,D)
    const float* ust   = (const float*)d_in[7];   // (U,D)
    const float* pre   = (const float*)d_in[8];   // (C,1,D)
    const float* suf   = (const float*)d_in[9];   // (C,1,D)
    const float* upre  = (const float*)d_in[10];  // (1,D)
    const float* usuf  = (const float*)d_in[11];  // (1,D)

    float* out = (float*)d_out;
    float* st_out = out + OUT2_ELEM_OFF;

    float* ws   = (float*)d_ws;
    float* sc_w = ws + WS_SC;
    float* part = ws + WS_PART;
    float* domp = ws + WS_DOM;
    float* semp = ws + WS_SEM;
    float* pp   = ws + WS_PP;

    hipLaunchKernelGGL(k_scores, dim3(Bb * 49), dim3(256), 0, stream, patch, query, sc_w);
    hipLaunchKernelGGL(k_pool_part, dim3(Bb * NPC), dim3(128), 0, stream, patch, sc_w, part);
    hipLaunchKernelGGL(k_combine, dim3(128), dim3(256), 0, stream, part, st_out);
    hipLaunchKernelGGL(k_proj, dim3(384), dim3(128), 0, stream,
                       gf, domW, domb, semW, st_out, domp, pp);
    hipLaunchKernelGGL(k_proj_sum, dim3(128), dim3(256), 0, stream, pp, semb, semp);
    hipLaunchKernelGGL(k_assemble, dim3(16160), dim3(128), 0, stream,
                       (const v4u*)pre, (const v4u*)suf,
                       (const v4u*)domp, (const v4u*)semp,
                       (const v4u*)upre, (const v4u*)usuf, (const v4u*)ust,
                       (v4u*)out, (v4u*)(out + OUT1_ELEM_OFF));
}